// Round 9
// baseline (111.384 us; speedup 1.0000x reference)
//
#include <hip/hip_runtime.h>

#define NFEAT 38

typedef __attribute__((ext_vector_type(8))) short bf16x8;
typedef __attribute__((ext_vector_type(4))) float f32x4;
typedef __attribute__((ext_vector_type(2))) float f32x2;

// bf16 table row bases
#define R_SP   0      // 512 fused species rows
#define R_AB   512    // 128 fused ability rows
#define R_IT   640    // 256 fused item rows
#define R_T1   896    // 404: (f3,f4,f5)   = f3*4+f4*2+f5
#define R_T2   1300   // 128: (f6,f11,f12) = f6*4+f11*2+f12  (hp=f6/31 folded in)
#define R_T3   1428   // 24 : (f7,f8)      = f7*8+f8
#define R_T4   1452   // 32 : (f9,f10)     = f9*2+f10
#define R_T5   1484   // 64 : (f13,f14,f15)= f13*8+f14*2+f15
#define R_T6   1548   // 169: (f16,f17)    = f16*13+f17
#define R_T7   1717   // 169: (f18,f19)
#define R_T8   1886   // 169: (f20,f21)
#define R_T9   2055   // 13 : f22
#define R_ACT  2068   // 512: actions_emb (bf16)
#define R_BITS 2580   // 5632: 2580 + fi*512 + half*256 + byte
#define NROWS  8212   // total rows (x 512 B = 4,204,544 B)

// k_prep block layout (1024 threads each)
#define B_FUSED  0     // 224 blocks: fused sp/ab/it rows (4 rows, 4-way K-split)
#define B_WBT    224   // 64 blocks : fragment-ordered bf16 mlp_w (wfrag)
#define B_BITS   288   // 1408 blocks: bits byte tables (4 rows/block)
#define B_MERGED 1696  // 421 blocks: merged one-hot/boost/action rows (4 rows/block)
#define NB_PREP  2117

__device__ __forceinline__ unsigned short f2bf(float f) {
    unsigned int u = __float_as_uint(f);
    u += 0x7fffu + ((u >> 16) & 1u);   // round-to-nearest-even
    return (unsigned short)(u >> 16);
}

// ---------------------------------------------------------------------------
// K0: table prep (fused rows / wfrag / bits tables / merged rows)
// ---------------------------------------------------------------------------
__global__ __launch_bounds__(1024) void k_prep(
    const float* __restrict__ sp_tbl, const float* __restrict__ ab_tbl,
    const float* __restrict__ it_tbl, const float* __restrict__ sp_emb,
    const float* __restrict__ ab_emb, const float* __restrict__ it_emb,
    const float* __restrict__ act_emb, const float* __restrict__ agg_w,
    const float* __restrict__ agg_b,  const float* __restrict__ mlp_w,
    unsigned short* __restrict__ tbl, unsigned short* __restrict__ wfrag)
{
    __shared__ float rowbuf[4 * 512];
    __shared__ float part[4][4][256];
    int blk = blockIdx.x, t = threadIdx.x, c = t & 255;
#define W(x) agg_w[(size_t)(x) * 256 + c]

    if (blk < B_WBT) {
        // ---- fused species/ability/item rows: 4 rows/block, K split 4 ways ----
        int r0 = blk << 2;
        const float* src; const float* emb; int len, wbase; bool add_b;
        if (r0 < 512)      { src = sp_tbl + (size_t)r0 * 512;           emb = sp_emb + (size_t)r0 * 256;           len = 512; wbase = 0;   add_b = true;  }
        else if (r0 < 640) { int q = r0 - 512; src = ab_tbl + (size_t)q * 128; emb = ab_emb + (size_t)q * 256; len = 128; wbase = 512; add_b = false; }
        else               { int q = r0 - 640; src = it_tbl + (size_t)q * 256; emb = it_emb + (size_t)q * 256; len = 256; wbase = 640; add_b = false; }
        int tot = len << 2;
        for (int i = t; i < tot; i += 1024) rowbuf[i] = src[i];
        __syncthreads();
        int kq   = t >> 8;
        int len4 = len >> 2;
        int kbeg = kq * len4, kend = kbeg + len4;
        float a0 = 0.f, a1 = 0.f, a2 = 0.f, a3 = 0.f;
        #pragma unroll 4
        for (int k = kbeg; k < kend; ++k) {
            float w = W(wbase + k);
            a0 += rowbuf[k] * w;
            a1 += rowbuf[len + k] * w;
            a2 += rowbuf[2 * len + k] * w;
            a3 += rowbuf[3 * len + k] * w;
        }
        part[0][kq][c] = a0; part[1][kq][c] = a1;
        part[2][kq][c] = a2; part[3][kq][c] = a3;
        __syncthreads();
        int row = t >> 8;
        float s = part[row][0][c] + part[row][1][c] + part[row][2][c] + part[row][3][c]
                + emb[row * 256 + c] + (add_b ? agg_b[c] : 0.f);
        tbl[(size_t)(r0 + row) * 256 + c] = f2bf(s);
        return;
    }
    if (blk < B_BITS) {
        // ---- fragment-ordered bf16 mlp_w:
        //      wfrag[((nt*8 + k0g)*64 + lane)*8 + j] = mlp_w[k0g*32 + (lane>>4)*8 + j][nt*16 + (lane&15)]
        int idx = ((blk - B_WBT) << 10) + t;   // 0..65535
        int j   = idx & 7;
        int fl  = (idx >> 3) & 63;
        int k0g = (idx >> 9) & 7;
        int nt  = idx >> 12;
        int k   = k0g * 32 + (fl >> 4) * 8 + j;
        int col = nt * 16 + (fl & 15);
        wfrag[idx] = f2bf(mlp_w[(size_t)k * 256 + col]);
        return;
    }
    if (blk < B_MERGED) {
        // ---- bits byte tables: 4 rows per block ----
        int idx = ((blk - B_BITS) << 10) + t;
        int row = idx >> 8;                 // 0..5631 = tseg*256 + byte
        int tseg = row >> 8, byte = row & 255;
        int base = 1171 + 16 * (tseg >> 1) + 8 * (tseg & 1);
        float acc = 0.f;
        #pragma unroll
        for (int j = 0; j < 8; ++j)
            if ((byte >> j) & 1) acc += W(base + j);
        tbl[(size_t)(R_BITS + row) * 256 + c] = f2bf(acc);
        return;
    }
    {
        // ---- merged category rows: 4 rows per block ----
        int r = ((blk - B_MERGED) << 2) + (t >> 8);   // 0..1683
        int row; float acc;
        if (r < 404)       { int f3 = r >> 2, f4 = (r >> 1) & 1, f5 = r & 1;
                             acc = W(896 + f3) + W(997 + f4) + W(999 + f5); row = R_T1 + r; }
        else if (r < 532)  { int i = r - 404; int f6 = i >> 2, f11 = (i >> 1) & 1, f12 = i & 1;
                             acc = W(1001 + f6) + (float)f6 * (1.f / 31.f) * W(1347)
                                 + W(1062 + f11) + W(1064 + f12); row = R_T2 + i; }
        else if (r < 556)  { int i = r - 532; acc = W(1033 + (i >> 3)) + W(1036 + (i & 7)); row = R_T3 + i; }
        else if (r < 588)  { int i = r - 556; acc = W(1044 + (i >> 1)) + W(1060 + (i & 1)); row = R_T4 + i; }
        else if (r < 652)  { int i = r - 588; acc = W(1066 + (i >> 3)) + W(1074 + ((i >> 1) & 3)) + W(1078 + (i & 1)); row = R_T5 + i; }
        else if (r < 821)  { int i = r - 652; acc = W(1080 + i / 13) + W(1093 + i % 13); row = R_T6 + i; }
        else if (r < 990)  { int i = r - 821; acc = W(1106 + i / 13) + W(1119 + i % 13); row = R_T7 + i; }
        else if (r < 1159) { int i = r - 990; acc = W(1132 + i / 13) + W(1145 + i % 13); row = R_T8 + i; }
        else if (r < 1172) { int i = r - 1159; acc = W(1158 + i); row = R_T9 + i; }
        else               { int i = r - 1172; acc = act_emb[(size_t)i * 256 + c]; row = R_ACT + i; }
        tbl[(size_t)row * 256 + c] = f2bf(acc);
    }
#undef W
}

// ---------------------------------------------------------------------------
// K1: per-entity packed row indices (10 aligned dwordx4 over a 160 B window).
// ---------------------------------------------------------------------------
__global__ __launch_bounds__(256) void k_idx(
    const int* __restrict__ ent, unsigned short* __restrict__ ridx)
{
    int e = blockIdx.x * 256 + threadIdx.x;
    size_t bb = (size_t)e * (NFEAT * 4);
    const uint4* wp = reinterpret_cast<const uint4*>(
        reinterpret_cast<const char*>(ent) + (bb & ~(size_t)15));
    uint4 q0 = wp[0], q1 = wp[1], q2 = wp[2], q3 = wp[3], q4 = wp[4];
    uint4 q5 = wp[5], q6 = wp[6], q7 = wp[7], q8 = wp[8], q9 = wp[9];
    unsigned int v[40] = {q0.x,q0.y,q0.z,q0.w, q1.x,q1.y,q1.z,q1.w,
                          q2.x,q2.y,q2.z,q2.w, q3.x,q3.y,q3.z,q3.w,
                          q4.x,q4.y,q4.z,q4.w, q5.x,q5.y,q5.z,q5.w,
                          q6.x,q6.y,q6.z,q6.w, q7.x,q7.y,q7.z,q7.w,
                          q8.x,q8.y,q8.z,q8.w, q9.x,q9.y,q9.z,q9.w};
    int f[NFEAT];
    if (e & 1) {
        #pragma unroll
        for (int i = 0; i < NFEAT; ++i) f[i] = (int)v[i + 2];
    } else {
        #pragma unroll
        for (int i = 0; i < NFEAT; ++i) f[i] = (int)v[i];
    }
    unsigned short r[40];
    r[0] = (unsigned short)f[0];
    r[1] = (unsigned short)(R_AB + f[1]);
    r[2] = (unsigned short)(R_IT + f[2]);
    r[3] = (unsigned short)(R_T1 + f[3] * 4 + f[4] * 2 + f[5]);
    r[4] = (unsigned short)(R_T2 + f[6] * 4 + f[11] * 2 + f[12]);
    r[5] = (unsigned short)(R_T3 + f[7] * 8 + f[8]);
    r[6] = (unsigned short)(R_T4 + f[9] * 2 + f[10]);
    r[7] = (unsigned short)(R_T5 + f[13] * 8 + f[14] * 2 + f[15]);
    r[8] = (unsigned short)(R_T6 + f[16] * 13 + f[17]);
    r[9] = (unsigned short)(R_T7 + f[18] * 13 + f[19]);
    r[10] = (unsigned short)(R_T8 + f[20] * 13 + f[21]);
    r[11] = (unsigned short)(R_T9 + f[22]);
    #pragma unroll
    for (int i = 0; i < 11; ++i) {
        int b = f[23 + i];
        r[12 + 2 * i] = (unsigned short)(R_BITS + i * 512 + (b & 255));
        r[13 + 2 * i] = (unsigned short)(R_BITS + i * 512 + 256 + ((b >> 8) & 255));
    }
    #pragma unroll
    for (int i = 0; i < 4; ++i) r[34 + i] = (unsigned short)(R_ACT + f[34 + i]);
    r[38] = 0; r[39] = 0;
    unsigned int p[20];
    #pragma unroll
    for (int i = 0; i < 20; ++i)
        p[i] = (unsigned int)r[2 * i] | ((unsigned int)r[2 * i + 1] << 16);
    uint4* dst = reinterpret_cast<uint4*>(ridx + (size_t)e * 40);
    dst[0] = make_uint4(p[0], p[1], p[2], p[3]);
    dst[1] = make_uint4(p[4], p[5], p[6], p[7]);
    dst[2] = make_uint4(p[8], p[9], p[10], p[11]);
    dst[3] = make_uint4(p[12], p[13], p[14], p[15]);
    dst[4] = make_uint4(p[16], p[17], p[18], p[19]);
}

// ---------------------------------------------------------------------------
// K2: fused encode + mlp.  Block = 512 threads (8 waves), 64 entities.
// Phase A: wave w encodes entities w*8..w*8+7.  Row indices are read via
//   readfirstlane-forced SCALAR loads (SGPR); each of the 38 table rows is a
//   wave-uniform global_load_dwordx2 (scalar base + lane*8 voffset) -> each
//   lane owns 4 cols, float2 packed accumulate, no shuffles, relu -> bf16
//   -> LDS (16B-unit XOR swizzle: unit ^= row&7).
// Phase B: wave w computes cols [w*32,w*32+32) for all 64 rows: 4 mt x 8 k0g
//   x 2 MFMA, B from fragment-ordered wfrag (scalar base), bias+mask, store.
// ---------------------------------------------------------------------------
__global__ __launch_bounds__(512) void k_fused_em(
    const unsigned short* __restrict__ ridx, const unsigned short* __restrict__ tbl,
    const unsigned short* __restrict__ wfrag, const float* __restrict__ mlp_b,
    float* __restrict__ out)
{
    __shared__ unsigned short xw[64 * 256];    // 32 KB
    __shared__ unsigned char  smask[64];
    int t    = threadIdx.x;
    int w    = t >> 6;
    int lane = t & 63;
    int wu   = __builtin_amdgcn_readfirstlane(w);
    int eb   = blockIdx.x << 6;
    const char* tb = reinterpret_cast<const char*>(tbl);
    char* xb = reinterpret_cast<char*>(xw);
    int v8   = lane << 3;                      // byte voffset into a 512B row

    // ---------------- phase A: encode 8 entities (rows wu*8..wu*8+7) --------
    for (int i = 0; i < 8; ++i) {
        int el = (wu << 3) + i;
        int eg = eb + el;
        const unsigned int* rq =
            reinterpret_cast<const unsigned int*>(ridx + (size_t)eg * 40);
        f32x2 aA = (f32x2){0.f, 0.f};          // cols {c0, c0+2}
        f32x2 aB = (f32x2){0.f, 0.f};          // cols {c0+1, c0+3}
        #pragma unroll
        for (int j = 0; j < 19; ++j) {
            unsigned int pj = rq[j];           // scalar (uniform) load
            int rE = (int)(pj & 0xffffu);
            int rO = (int)(pj >> 16);
            uint2 vE = *reinterpret_cast<const uint2*>(tb + ((size_t)rE << 9) + v8);
            uint2 vO = *reinterpret_cast<const uint2*>(tb + ((size_t)rO << 9) + v8);
            aA += (f32x2){__uint_as_float(vE.x << 16), __uint_as_float(vE.y << 16)};
            aB += (f32x2){__uint_as_float(vE.x & 0xffff0000u), __uint_as_float(vE.y & 0xffff0000u)};
            aA += (f32x2){__uint_as_float(vO.x << 16), __uint_as_float(vO.y << 16)};
            aB += (f32x2){__uint_as_float(vO.x & 0xffff0000u), __uint_as_float(vO.y & 0xffff0000u)};
        }
        if (lane == 0) smask[el] = ((rq[0] & 0xffffu) < 2u) ? 1 : 0;
        unsigned int o0 = (unsigned)f2bf(fmaxf(aA[0], 0.f)) | ((unsigned)f2bf(fmaxf(aB[0], 0.f)) << 16);
        unsigned int o1 = (unsigned)f2bf(fmaxf(aA[1], 0.f)) | ((unsigned)f2bf(fmaxf(aB[1], 0.f)) << 16);
        int u  = lane >> 1;
        int up = u ^ (el & 7);
        *reinterpret_cast<uint2*>(xb + (el << 9) + (up << 4) + ((lane & 1) << 3)) =
            make_uint2(o0, o1);
    }
    __syncthreads();

    // ---------------- phase B: 64 rows x 32 cols via MFMA -------------------
    int rc = lane & 15;
    int kg = lane >> 4;
    int nt0 = wu << 1;

    f32x4 acc0[4], acc1[4];
    #pragma unroll
    for (int mt = 0; mt < 4; ++mt) {
        acc0[mt] = (f32x4){0.f, 0.f, 0.f, 0.f};
        acc1[mt] = (f32x4){0.f, 0.f, 0.f, 0.f};
    }

    #pragma unroll
    for (int k0g = 0; k0g < 8; ++k0g) {
        bf16x8 b0 = *reinterpret_cast<const bf16x8*>(
            wfrag + (((size_t)(nt0 * 8 + k0g)) << 9) + (lane << 3));
        bf16x8 b1 = *reinterpret_cast<const bf16x8*>(
            wfrag + (((size_t)((nt0 + 1) * 8 + k0g)) << 9) + (lane << 3));
        int up = ((k0g << 2) + kg) ^ (rc & 7);
        #pragma unroll
        for (int mt = 0; mt < 4; ++mt) {
            int r = (mt << 4) + rc;
            bf16x8 a = *reinterpret_cast<const bf16x8*>(xb + (r << 9) + (up << 4));
            acc0[mt] = __builtin_amdgcn_mfma_f32_16x16x32_bf16(a, b0, acc0[mt], 0, 0, 0);
            acc1[mt] = __builtin_amdgcn_mfma_f32_16x16x32_bf16(a, b1, acc1[mt], 0, 0, 0);
        }
    }

    int c0 = wu << 5;
    float bias0 = mlp_b[c0 + rc];
    float bias1 = mlp_b[c0 + 16 + rc];
    #pragma unroll
    for (int mt = 0; mt < 4; ++mt) {
        unsigned int mw = *reinterpret_cast<const unsigned int*>(&smask[(mt << 4) + (kg << 2)]);
        #pragma unroll
        for (int j = 0; j < 4; ++j) {
            int row = eb + (mt << 4) + (kg << 2) + j;
            bool m = (mw >> (8 * j)) & 1u;
            out[(size_t)row * 256 + c0 + rc]      = m ? 0.f : (acc0[mt][j] + bias0);
            out[(size_t)row * 256 + c0 + 16 + rc] = m ? 0.f : (acc1[mt][j] + bias1);
        }
    }
}

// ---------------------------------------------------------------------------
extern "C" void kernel_launch(void* const* d_in, const int* in_sizes, int n_in,
                              void* d_out, int out_size, void* d_ws, size_t ws_size,
                              hipStream_t stream)
{
    const int*   ent     = (const int*)d_in[0];
    const float* sp_tbl  = (const float*)d_in[1];
    const float* ab_tbl  = (const float*)d_in[2];
    const float* it_tbl  = (const float*)d_in[3];
    const float* sp_emb  = (const float*)d_in[4];
    const float* ab_emb  = (const float*)d_in[5];
    const float* it_emb  = (const float*)d_in[6];
    const float* act_emb = (const float*)d_in[7];
    const float* agg_w   = (const float*)d_in[8];
    const float* agg_b   = (const float*)d_in[9];
    const float* mlp_w   = (const float*)d_in[10];
    const float* mlp_b   = (const float*)d_in[11];
    float* out = (float*)d_out;

    char* ws = (char*)d_ws;
    unsigned short* tbl   = (unsigned short*)(ws);               // 8212*512 = 4,204,544 B
    unsigned short* wfrag = (unsigned short*)(ws + 4204544);     //   131,072 B
    unsigned short* ridx  = (unsigned short*)(ws + 4335616);     // 65536*80 = 5,242,880 B

    k_prep    <<<dim3(NB_PREP), dim3(1024), 0, stream>>>(sp_tbl, ab_tbl, it_tbl,
                                                         sp_emb, ab_emb, it_emb,
                                                         act_emb, agg_w, agg_b, mlp_w,
                                                         tbl, wfrag);
    k_idx     <<<dim3(256),     dim3(256),  0, stream>>>(ent, ridx);
    k_fused_em<<<dim3(1024),    dim3(512),  0, stream>>>(ridx, tbl, wfrag, mlp_b, out);
}

// Round 10
// 93.011 us; speedup vs baseline: 1.1975x; 1.1975x over previous
//
#include <hip/hip_runtime.h>

#define NFEAT 38

typedef __attribute__((ext_vector_type(8))) short bf16x8;
typedef __attribute__((ext_vector_type(4))) float f32x4;
typedef __attribute__((ext_vector_type(2))) float f32x2;

// bf16 table row bases
#define R_SP   0      // 512 fused species rows
#define R_AB   512    // 128 fused ability rows
#define R_IT   640    // 256 fused item rows
#define R_T1   896    // 404: (f3,f4,f5)   = f3*4+f4*2+f5
#define R_T2   1300   // 128: (f6,f11,f12) = f6*4+f11*2+f12  (hp=f6/31 folded in)
#define R_T3   1428   // 24 : (f7,f8)      = f7*8+f8
#define R_T4   1452   // 32 : (f9,f10)     = f9*2+f10
#define R_T5   1484   // 64 : (f13,f14,f15)= f13*8+f14*2+f15
#define R_T6   1548   // 169: (f16,f17)    = f16*13+f17
#define R_T7   1717   // 169: (f18,f19)
#define R_T8   1886   // 169: (f20,f21)
#define R_T9   2055   // 13 : f22
#define R_ACT  2068   // 512: actions_emb (bf16)
#define R_BITS 2580   // 5632: 2580 + fi*512 + half*256 + byte
#define NROWS  8212   // total rows (x 512 B = 4,204,544 B)

// k_prep block layout (1024 threads each)
#define B_FUSED  0     // 224 blocks: fused sp/ab/it rows (4 rows, 4-way K-split)
#define B_WBT    224   // 64 blocks : fragment-ordered bf16 mlp_w (wfrag)
#define B_BITS   288   // 1408 blocks: bits byte tables (4 rows/block)
#define B_MERGED 1696  // 421 blocks: merged one-hot/boost/action rows (4 rows/block)
#define B_IDX    2117  // 64 blocks : per-entity packed row indices
#define NB_PREP  2181

__device__ __forceinline__ unsigned short f2bf(float f) {
    unsigned int u = __float_as_uint(f);
    u += 0x7fffu + ((u >> 16) & 1u);   // round-to-nearest-even
    return (unsigned short)(u >> 16);
}

// ---------------------------------------------------------------------------
// K0: table prep (fused rows / wfrag / bits tables / merged rows / ridx)
// ---------------------------------------------------------------------------
__global__ __launch_bounds__(1024) void k_prep(
    const float* __restrict__ sp_tbl, const float* __restrict__ ab_tbl,
    const float* __restrict__ it_tbl, const float* __restrict__ sp_emb,
    const float* __restrict__ ab_emb, const float* __restrict__ it_emb,
    const float* __restrict__ act_emb, const float* __restrict__ agg_w,
    const float* __restrict__ agg_b,  const float* __restrict__ mlp_w,
    const int* __restrict__ ent,
    unsigned short* __restrict__ tbl, unsigned short* __restrict__ wfrag,
    unsigned short* __restrict__ ridx)
{
    __shared__ float rowbuf[4 * 512];
    __shared__ float part[4][4][256];
    int blk = blockIdx.x, t = threadIdx.x, c = t & 255;
#define W(x) agg_w[(size_t)(x) * 256 + c]

    if (blk < B_WBT) {
        // ---- fused species/ability/item rows: 4 rows/block, K split 4 ways ----
        int r0 = blk << 2;
        const float* src; const float* emb; int len, wbase; bool add_b;
        if (r0 < 512)      { src = sp_tbl + (size_t)r0 * 512;           emb = sp_emb + (size_t)r0 * 256;           len = 512; wbase = 0;   add_b = true;  }
        else if (r0 < 640) { int q = r0 - 512; src = ab_tbl + (size_t)q * 128; emb = ab_emb + (size_t)q * 256; len = 128; wbase = 512; add_b = false; }
        else               { int q = r0 - 640; src = it_tbl + (size_t)q * 256; emb = it_emb + (size_t)q * 256; len = 256; wbase = 640; add_b = false; }
        int tot = len << 2;
        for (int i = t; i < tot; i += 1024) rowbuf[i] = src[i];
        __syncthreads();
        int kq   = t >> 8;
        int len4 = len >> 2;
        int kbeg = kq * len4, kend = kbeg + len4;
        float a0 = 0.f, a1 = 0.f, a2 = 0.f, a3 = 0.f;
        #pragma unroll 4
        for (int k = kbeg; k < kend; ++k) {
            float w = W(wbase + k);
            a0 += rowbuf[k] * w;
            a1 += rowbuf[len + k] * w;
            a2 += rowbuf[2 * len + k] * w;
            a3 += rowbuf[3 * len + k] * w;
        }
        part[0][kq][c] = a0; part[1][kq][c] = a1;
        part[2][kq][c] = a2; part[3][kq][c] = a3;
        __syncthreads();
        int row = t >> 8;
        float s = part[row][0][c] + part[row][1][c] + part[row][2][c] + part[row][3][c]
                + emb[row * 256 + c] + (add_b ? agg_b[c] : 0.f);
        tbl[(size_t)(r0 + row) * 256 + c] = f2bf(s);
        return;
    }
    if (blk < B_BITS) {
        // ---- fragment-ordered bf16 mlp_w:
        //      wfrag[((nt*8 + k0g)*64 + lane)*8 + j] = mlp_w[k0g*32 + (lane>>4)*8 + j][nt*16 + (lane&15)]
        int idx = ((blk - B_WBT) << 10) + t;   // 0..65535
        int j   = idx & 7;
        int fl  = (idx >> 3) & 63;
        int k0g = (idx >> 9) & 7;
        int nt  = idx >> 12;
        int k   = k0g * 32 + (fl >> 4) * 8 + j;
        int col = nt * 16 + (fl & 15);
        wfrag[idx] = f2bf(mlp_w[(size_t)k * 256 + col]);
        return;
    }
    if (blk < B_MERGED) {
        // ---- bits byte tables: 4 rows per block ----
        int idx = ((blk - B_BITS) << 10) + t;
        int row = idx >> 8;                 // 0..5631 = tseg*256 + byte
        int tseg = row >> 8, byte = row & 255;
        int base = 1171 + 16 * (tseg >> 1) + 8 * (tseg & 1);
        float acc = 0.f;
        #pragma unroll
        for (int j = 0; j < 8; ++j)
            if ((byte >> j) & 1) acc += W(base + j);
        tbl[(size_t)(R_BITS + row) * 256 + c] = f2bf(acc);
        return;
    }
    if (blk < B_IDX) {
        // ---- merged category rows: 4 rows per block ----
        int r = ((blk - B_MERGED) << 2) + (t >> 8);   // 0..1683
        int row; float acc;
        if (r < 404)       { int f3 = r >> 2, f4 = (r >> 1) & 1, f5 = r & 1;
                             acc = W(896 + f3) + W(997 + f4) + W(999 + f5); row = R_T1 + r; }
        else if (r < 532)  { int i = r - 404; int f6 = i >> 2, f11 = (i >> 1) & 1, f12 = i & 1;
                             acc = W(1001 + f6) + (float)f6 * (1.f / 31.f) * W(1347)
                                 + W(1062 + f11) + W(1064 + f12); row = R_T2 + i; }
        else if (r < 556)  { int i = r - 532; acc = W(1033 + (i >> 3)) + W(1036 + (i & 7)); row = R_T3 + i; }
        else if (r < 588)  { int i = r - 556; acc = W(1044 + (i >> 1)) + W(1060 + (i & 1)); row = R_T4 + i; }
        else if (r < 652)  { int i = r - 588; acc = W(1066 + (i >> 3)) + W(1074 + ((i >> 1) & 3)) + W(1078 + (i & 1)); row = R_T5 + i; }
        else if (r < 821)  { int i = r - 652; acc = W(1080 + i / 13) + W(1093 + i % 13); row = R_T6 + i; }
        else if (r < 990)  { int i = r - 821; acc = W(1106 + i / 13) + W(1119 + i % 13); row = R_T7 + i; }
        else if (r < 1159) { int i = r - 990; acc = W(1132 + i / 13) + W(1145 + i % 13); row = R_T8 + i; }
        else if (r < 1172) { int i = r - 1159; acc = W(1158 + i); row = R_T9 + i; }
        else               { int i = r - 1172; acc = act_emb[(size_t)i * 256 + c]; row = R_ACT + i; }
        tbl[(size_t)row * 256 + c] = f2bf(acc);
        return;
    }
    {
        // ---- per-entity packed row indices (windowed dwordx4 loads) ----
        int e = ((blk - B_IDX) << 10) + t;
        size_t bb = (size_t)e * (NFEAT * 4);
        const uint4* wp = reinterpret_cast<const uint4*>(
            reinterpret_cast<const char*>(ent) + (bb & ~(size_t)15));
        uint4 q0 = wp[0], q1 = wp[1], q2 = wp[2], q3 = wp[3], q4 = wp[4];
        uint4 q5 = wp[5], q6 = wp[6], q7 = wp[7], q8 = wp[8], q9 = wp[9];
        unsigned int v[40] = {q0.x,q0.y,q0.z,q0.w, q1.x,q1.y,q1.z,q1.w,
                              q2.x,q2.y,q2.z,q2.w, q3.x,q3.y,q3.z,q3.w,
                              q4.x,q4.y,q4.z,q4.w, q5.x,q5.y,q5.z,q5.w,
                              q6.x,q6.y,q6.z,q6.w, q7.x,q7.y,q7.z,q7.w,
                              q8.x,q8.y,q8.z,q8.w, q9.x,q9.y,q9.z,q9.w};
        int f[NFEAT];
        if (e & 1) {
            #pragma unroll
            for (int i = 0; i < NFEAT; ++i) f[i] = (int)v[i + 2];
        } else {
            #pragma unroll
            for (int i = 0; i < NFEAT; ++i) f[i] = (int)v[i];
        }
        unsigned short r[40];
        r[0] = (unsigned short)f[0];
        r[1] = (unsigned short)(R_AB + f[1]);
        r[2] = (unsigned short)(R_IT + f[2]);
        r[3] = (unsigned short)(R_T1 + f[3] * 4 + f[4] * 2 + f[5]);
        r[4] = (unsigned short)(R_T2 + f[6] * 4 + f[11] * 2 + f[12]);
        r[5] = (unsigned short)(R_T3 + f[7] * 8 + f[8]);
        r[6] = (unsigned short)(R_T4 + f[9] * 2 + f[10]);
        r[7] = (unsigned short)(R_T5 + f[13] * 8 + f[14] * 2 + f[15]);
        r[8] = (unsigned short)(R_T6 + f[16] * 13 + f[17]);
        r[9] = (unsigned short)(R_T7 + f[18] * 13 + f[19]);
        r[10] = (unsigned short)(R_T8 + f[20] * 13 + f[21]);
        r[11] = (unsigned short)(R_T9 + f[22]);
        #pragma unroll
        for (int i = 0; i < 11; ++i) {
            int b = f[23 + i];
            r[12 + 2 * i] = (unsigned short)(R_BITS + i * 512 + (b & 255));
            r[13 + 2 * i] = (unsigned short)(R_BITS + i * 512 + 256 + ((b >> 8) & 255));
        }
        #pragma unroll
        for (int i = 0; i < 4; ++i) r[34 + i] = (unsigned short)(R_ACT + f[34 + i]);
        r[38] = 0; r[39] = 0;
        unsigned int p[20];
        #pragma unroll
        for (int i = 0; i < 20; ++i)
            p[i] = (unsigned int)r[2 * i] | ((unsigned int)r[2 * i + 1] << 16);
        uint4* dst = reinterpret_cast<uint4*>(ridx + (size_t)e * 40);
        dst[0] = make_uint4(p[0], p[1], p[2], p[3]);
        dst[1] = make_uint4(p[4], p[5], p[6], p[7]);
        dst[2] = make_uint4(p[8], p[9], p[10], p[11]);
        dst[3] = make_uint4(p[12], p[13], p[14], p[15]);
        dst[4] = make_uint4(p[16], p[17], p[18], p[19]);
    }
#undef W
}

// ---------------------------------------------------------------------------
// K1: fused encode + mlp.  Block = 512 threads (8 waves), 64 entities.
// Phase A: wave w encodes entities w*8..w*8+7.  Per entity: ALL 19 paired
//   16B gather loads issued into registers BEFORE consumption (one latency
//   exposure); lanes 0-31 take even rows, 32-63 odd rows; packed-f32
//   accumulate; 8x shfl_xor(32) combine; relu -> bf16 -> LDS (16B-unit XOR
//   swizzle: unit ^= row&7).
// Phase B: wave w computes cols [w*32,w*32+32) for all 64 rows: 4 mt x 8 k0g
//   x 2 MFMA, B from fragment-ordered wfrag, bias+mask, store.
// ---------------------------------------------------------------------------
__global__ __launch_bounds__(512, 2) void k_fused_em(
    const unsigned short* __restrict__ ridx, const unsigned short* __restrict__ tbl,
    const unsigned short* __restrict__ wfrag, const float* __restrict__ mlp_b,
    float* __restrict__ out)
{
    __shared__ unsigned short xw[64 * 256];    // 32 KB
    __shared__ unsigned char  smask[64];
    int t    = threadIdx.x;
    int w    = t >> 6;
    int lane = t & 63;
    int half = lane >> 5;
    int cp   = lane & 31;
    int wu   = __builtin_amdgcn_readfirstlane(w);
    int eb   = blockIdx.x << 6;
    const char* tb = reinterpret_cast<const char*>(tbl) + ((size_t)cp << 4);
    char* xb = reinterpret_cast<char*>(xw);

    // ---------------- phase A: encode 8 entities (rows wu*8..wu*8+7) --------
    for (int i = 0; i < 8; ++i) {
        int el = (wu << 3) + i;
        int eg = eb + el;
        const unsigned int* rq =
            reinterpret_cast<const unsigned int*>(ridx + (size_t)eg * 40);
        uint4 v[19];
        #pragma unroll
        for (int j = 0; j < 19; ++j) {
            unsigned int pj = rq[j];                        // scalar (uniform)
            unsigned int row = half ? (pj >> 16) : (pj & 0xffffu);
            v[j] = *reinterpret_cast<const uint4*>(tb + ((size_t)row << 9));
        }
        f32x2 aE0 = (f32x2){0.f, 0.f}, aO0 = (f32x2){0.f, 0.f};
        f32x2 aE1 = (f32x2){0.f, 0.f}, aO1 = (f32x2){0.f, 0.f};
        #pragma unroll
        for (int j = 0; j < 19; ++j) {
            aE0 += (f32x2){__uint_as_float(v[j].x << 16),        __uint_as_float(v[j].y << 16)};
            aO0 += (f32x2){__uint_as_float(v[j].x & 0xffff0000u), __uint_as_float(v[j].y & 0xffff0000u)};
            aE1 += (f32x2){__uint_as_float(v[j].z << 16),        __uint_as_float(v[j].w << 16)};
            aO1 += (f32x2){__uint_as_float(v[j].z & 0xffff0000u), __uint_as_float(v[j].w & 0xffff0000u)};
        }
        float s0 = aE0[0] + __shfl_xor(aE0[0], 32);
        float s1 = aO0[0] + __shfl_xor(aO0[0], 32);
        float s2 = aE0[1] + __shfl_xor(aE0[1], 32);
        float s3 = aO0[1] + __shfl_xor(aO0[1], 32);
        float s4 = aE1[0] + __shfl_xor(aE1[0], 32);
        float s5 = aO1[0] + __shfl_xor(aO1[0], 32);
        float s6 = aE1[1] + __shfl_xor(aE1[1], 32);
        float s7 = aO1[1] + __shfl_xor(aO1[1], 32);
        if (lane == 0) smask[el] = ((rq[0] & 0xffffu) < 2u) ? 1 : 0;
        if (half == 0) {
            unsigned int o0 = (unsigned)f2bf(fmaxf(s0, 0.f)) | ((unsigned)f2bf(fmaxf(s1, 0.f)) << 16);
            unsigned int o1 = (unsigned)f2bf(fmaxf(s2, 0.f)) | ((unsigned)f2bf(fmaxf(s3, 0.f)) << 16);
            unsigned int o2 = (unsigned)f2bf(fmaxf(s4, 0.f)) | ((unsigned)f2bf(fmaxf(s5, 0.f)) << 16);
            unsigned int o3 = (unsigned)f2bf(fmaxf(s6, 0.f)) | ((unsigned)f2bf(fmaxf(s7, 0.f)) << 16);
            int up = cp ^ (el & 7);
            *reinterpret_cast<uint4*>(xb + (el << 9) + (up << 4)) = make_uint4(o0, o1, o2, o3);
        }
    }
    __syncthreads();

    // ---------------- phase B: 64 rows x 32 cols via MFMA -------------------
    int rc = lane & 15;
    int kg = lane >> 4;
    int nt0 = wu << 1;

    f32x4 acc0[4], acc1[4];
    #pragma unroll
    for (int mt = 0; mt < 4; ++mt) {
        acc0[mt] = (f32x4){0.f, 0.f, 0.f, 0.f};
        acc1[mt] = (f32x4){0.f, 0.f, 0.f, 0.f};
    }

    #pragma unroll
    for (int k0g = 0; k0g < 8; ++k0g) {
        bf16x8 b0 = *reinterpret_cast<const bf16x8*>(
            wfrag + (((size_t)(nt0 * 8 + k0g)) << 9) + (lane << 3));
        bf16x8 b1 = *reinterpret_cast<const bf16x8*>(
            wfrag + (((size_t)((nt0 + 1) * 8 + k0g)) << 9) + (lane << 3));
        int up = ((k0g << 2) + kg) ^ (rc & 7);
        #pragma unroll
        for (int mt = 0; mt < 4; ++mt) {
            int r = (mt << 4) + rc;
            bf16x8 a = *reinterpret_cast<const bf16x8*>(xb + (r << 9) + (up << 4));
            acc0[mt] = __builtin_amdgcn_mfma_f32_16x16x32_bf16(a, b0, acc0[mt], 0, 0, 0);
            acc1[mt] = __builtin_amdgcn_mfma_f32_16x16x32_bf16(a, b1, acc1[mt], 0, 0, 0);
        }
    }

    int c0 = wu << 5;
    float bias0 = mlp_b[c0 + rc];
    float bias1 = mlp_b[c0 + 16 + rc];
    #pragma unroll
    for (int mt = 0; mt < 4; ++mt) {
        unsigned int mw = *reinterpret_cast<const unsigned int*>(&smask[(mt << 4) + (kg << 2)]);
        #pragma unroll
        for (int j = 0; j < 4; ++j) {
            int row = eb + (mt << 4) + (kg << 2) + j;
            bool m = (mw >> (8 * j)) & 1u;
            out[(size_t)row * 256 + c0 + rc]      = m ? 0.f : (acc0[mt][j] + bias0);
            out[(size_t)row * 256 + c0 + 16 + rc] = m ? 0.f : (acc1[mt][j] + bias1);
        }
    }
}

// ---------------------------------------------------------------------------
extern "C" void kernel_launch(void* const* d_in, const int* in_sizes, int n_in,
                              void* d_out, int out_size, void* d_ws, size_t ws_size,
                              hipStream_t stream)
{
    const int*   ent     = (const int*)d_in[0];
    const float* sp_tbl  = (const float*)d_in[1];
    const float* ab_tbl  = (const float*)d_in[2];
    const float* it_tbl  = (const float*)d_in[3];
    const float* sp_emb  = (const float*)d_in[4];
    const float* ab_emb  = (const float*)d_in[5];
    const float* it_emb  = (const float*)d_in[6];
    const float* act_emb = (const float*)d_in[7];
    const float* agg_w   = (const float*)d_in[8];
    const float* agg_b   = (const float*)d_in[9];
    const float* mlp_w   = (const float*)d_in[10];
    const float* mlp_b   = (const float*)d_in[11];
    float* out = (float*)d_out;

    char* ws = (char*)d_ws;
    unsigned short* tbl   = (unsigned short*)(ws);               // 8212*512 = 4,204,544 B
    unsigned short* wfrag = (unsigned short*)(ws + 4204544);     //   131,072 B
    unsigned short* ridx  = (unsigned short*)(ws + 4335616);     // 65536*80 = 5,242,880 B

    k_prep    <<<dim3(NB_PREP), dim3(1024), 0, stream>>>(sp_tbl, ab_tbl, it_tbl,
                                                         sp_emb, ab_emb, it_emb,
                                                         act_emb, agg_w, agg_b, mlp_w,
                                                         ent, tbl, wfrag, ridx);
    k_fused_em<<<dim3(1024),    dim3(512),  0, stream>>>(ridx, tbl, wfrag, mlp_b, out);
}

// Round 11
// 66.196 us; speedup vs baseline: 1.6826x; 1.4051x over previous
//
#include <hip/hip_runtime.h>

#define NFEAT 38

typedef __attribute__((ext_vector_type(8))) short bf16x8;
typedef __attribute__((ext_vector_type(4))) float f32x4;
typedef __attribute__((ext_vector_type(2))) float f32x2;
typedef __attribute__((ext_vector_type(4))) unsigned int u32x4;

// bf16 table row bases (rows of 256 cols, 512 B)
#define R_SP   0      // 512 fused species rows
#define R_AB   512    // 128 fused ability rows
#define R_IT   640    // 256 fused item rows
#define R_T1   896    // 404: (f3,f4,f5)
#define R_T2   1300   // 128: (f6,f11,f12), hp folded
#define R_T3   1428   // 24 : (f7,f8)
#define R_T4   1452   // 32 : (f9,f10)
#define R_T5   1484   // 64 : (f13,f14,f15)
#define R_T6   1548   // 169: (f16,f17)
#define R_T7   1717   // 169: (f18,f19)
#define R_T8   1886   // 169: (f20,f21)
#define R_T9   2055   // 13 : f22
#define R_ACT  2068   // 512: actions_emb
#define NROWS  2580   // 1,320,960 B  (fits one XCD L2)

// k_prep block layout (1024 threads each)
#define B_FUSED  0     // 224: fused sp/ab/it rows
#define B_WMLP   224   // 64 : fragment-ordered bf16 mlp_w
#define B_WBITS  288   // 48 : fragment-ordered bf16 bits-weights (192x256, padded)
#define B_MERGED 336   // 421: merged one-hot/boost/action rows
#define B_IDXS   757   // 64 : per-entity packed ridx (16 rows + 6 bitwords)
#define NB_PREP  821

__device__ __forceinline__ unsigned short f2bf(float f) {
    unsigned int u = __float_as_uint(f);
    u += 0x7fffu + ((u >> 16) & 1u);   // round-to-nearest-even
    return (unsigned short)(u >> 16);
}

// ---------------------------------------------------------------------------
// K0: all prep
// ---------------------------------------------------------------------------
__global__ __launch_bounds__(1024) void k_prep(
    const float* __restrict__ sp_tbl, const float* __restrict__ ab_tbl,
    const float* __restrict__ it_tbl, const float* __restrict__ sp_emb,
    const float* __restrict__ ab_emb, const float* __restrict__ it_emb,
    const float* __restrict__ act_emb, const float* __restrict__ agg_w,
    const float* __restrict__ agg_b,  const float* __restrict__ mlp_w,
    const int* __restrict__ ent,
    unsigned short* __restrict__ tbl, unsigned short* __restrict__ wfrag,
    unsigned short* __restrict__ wbits, unsigned int* __restrict__ ridx)
{
    __shared__ float rowbuf[4 * 512];
    __shared__ float part[4][4][256];
    int blk = blockIdx.x, t = threadIdx.x, c = t & 255;
#define W(x) agg_w[(size_t)(x) * 256 + c]

    if (blk < B_WMLP) {
        // ---- fused species/ability/item rows: 4 rows/block, K split 4 ways ----
        int r0 = blk << 2;
        const float* src; const float* emb; int len, wbase; bool add_b;
        if (r0 < 512)      { src = sp_tbl + (size_t)r0 * 512;           emb = sp_emb + (size_t)r0 * 256;           len = 512; wbase = 0;   add_b = true;  }
        else if (r0 < 640) { int q = r0 - 512; src = ab_tbl + (size_t)q * 128; emb = ab_emb + (size_t)q * 256; len = 128; wbase = 512; add_b = false; }
        else               { int q = r0 - 640; src = it_tbl + (size_t)q * 256; emb = it_emb + (size_t)q * 256; len = 256; wbase = 640; add_b = false; }
        int tot = len << 2;
        for (int i = t; i < tot; i += 1024) rowbuf[i] = src[i];
        __syncthreads();
        int kq   = t >> 8;
        int len4 = len >> 2;
        int kbeg = kq * len4, kend = kbeg + len4;
        float a0 = 0.f, a1 = 0.f, a2 = 0.f, a3 = 0.f;
        #pragma unroll 4
        for (int k = kbeg; k < kend; ++k) {
            float w = W(wbase + k);
            a0 += rowbuf[k] * w;
            a1 += rowbuf[len + k] * w;
            a2 += rowbuf[2 * len + k] * w;
            a3 += rowbuf[3 * len + k] * w;
        }
        part[0][kq][c] = a0; part[1][kq][c] = a1;
        part[2][kq][c] = a2; part[3][kq][c] = a3;
        __syncthreads();
        int row = t >> 8;
        float s = part[row][0][c] + part[row][1][c] + part[row][2][c] + part[row][3][c]
                + emb[row * 256 + c] + (add_b ? agg_b[c] : 0.f);
        tbl[(size_t)(r0 + row) * 256 + c] = f2bf(s);
        return;
    }
    if (blk < B_WBITS) {
        // ---- fragment-ordered bf16 mlp_w ----
        int idx = ((blk - B_WMLP) << 10) + t;   // 0..65535
        int j   = idx & 7;
        int fl  = (idx >> 3) & 63;
        int k0g = (idx >> 9) & 7;
        int nt  = idx >> 12;
        int k   = k0g * 32 + (fl >> 4) * 8 + j;
        int col = nt * 16 + (fl & 15);
        wfrag[idx] = f2bf(mlp_w[(size_t)k * 256 + col]);
        return;
    }
    if (blk < B_MERGED) {
        // ---- fragment-ordered bf16 bits-weights: rows 1171..1346 of agg_w,
        //      wbits[((nt*6+kt)*64+lane)*8+j] = agg_w[1171 + kt*32 + (lane>>4)*8 + j][nt*16 + (lane&15)]
        int idx = ((blk - B_WBITS) << 10) + t;  // 0..49151
        int j   = idx & 7;
        int ln  = (idx >> 3) & 63;
        int r2  = idx >> 9;                     // 0..95
        int kt  = r2 % 6;
        int nt  = r2 / 6;
        int k   = kt * 32 + ((ln >> 4) << 3) + j;
        int col = (nt << 4) + (ln & 15);
        float v = (k < 176) ? agg_w[(size_t)(1171 + k) * 256 + col] : 0.f;
        wbits[idx] = f2bf(v);
        return;
    }
    if (blk < B_IDXS) {
        // ---- merged category rows: 4 rows per block ----
        int r = ((blk - B_MERGED) << 2) + (t >> 8);   // 0..1683
        int row; float acc;
        if (r < 404)       { int f3 = r >> 2, f4 = (r >> 1) & 1, f5 = r & 1;
                             acc = W(896 + f3) + W(997 + f4) + W(999 + f5); row = R_T1 + r; }
        else if (r < 532)  { int i = r - 404; int f6 = i >> 2, f11 = (i >> 1) & 1, f12 = i & 1;
                             acc = W(1001 + f6) + (float)f6 * (1.f / 31.f) * W(1347)
                                 + W(1062 + f11) + W(1064 + f12); row = R_T2 + i; }
        else if (r < 556)  { int i = r - 532; acc = W(1033 + (i >> 3)) + W(1036 + (i & 7)); row = R_T3 + i; }
        else if (r < 588)  { int i = r - 556; acc = W(1044 + (i >> 1)) + W(1060 + (i & 1)); row = R_T4 + i; }
        else if (r < 652)  { int i = r - 588; acc = W(1066 + (i >> 3)) + W(1074 + ((i >> 1) & 3)) + W(1078 + (i & 1)); row = R_T5 + i; }
        else if (r < 821)  { int i = r - 652; acc = W(1080 + i / 13) + W(1093 + i % 13); row = R_T6 + i; }
        else if (r < 990)  { int i = r - 821; acc = W(1106 + i / 13) + W(1119 + i % 13); row = R_T7 + i; }
        else if (r < 1159) { int i = r - 990; acc = W(1132 + i / 13) + W(1145 + i % 13); row = R_T8 + i; }
        else if (r < 1172) { int i = r - 1159; acc = W(1158 + i); row = R_T9 + i; }
        else               { int i = r - 1172; acc = act_emb[(size_t)i * 256 + c]; row = R_ACT + i; }
        tbl[(size_t)row * 256 + c] = f2bf(acc);
        return;
    }
    {
        // ---- per-entity packed ridx: 8 row-pairs + 6 bitwords + pad = 64 B ----
        int e = ((blk - B_IDXS) << 10) + t;
        size_t bb = (size_t)e * (NFEAT * 4);
        const uint4* wp = reinterpret_cast<const uint4*>(
            reinterpret_cast<const char*>(ent) + (bb & ~(size_t)15));
        uint4 q0 = wp[0], q1 = wp[1], q2 = wp[2], q3 = wp[3], q4 = wp[4];
        uint4 q5 = wp[5], q6 = wp[6], q7 = wp[7], q8 = wp[8], q9 = wp[9];
        unsigned int v[40] = {q0.x,q0.y,q0.z,q0.w, q1.x,q1.y,q1.z,q1.w,
                              q2.x,q2.y,q2.z,q2.w, q3.x,q3.y,q3.z,q3.w,
                              q4.x,q4.y,q4.z,q4.w, q5.x,q5.y,q5.z,q5.w,
                              q6.x,q6.y,q6.z,q6.w, q7.x,q7.y,q7.z,q7.w,
                              q8.x,q8.y,q8.z,q8.w, q9.x,q9.y,q9.z,q9.w};
        int f[NFEAT];
        if (e & 1) {
            #pragma unroll
            for (int i = 0; i < NFEAT; ++i) f[i] = (int)v[i + 2];
        } else {
            #pragma unroll
            for (int i = 0; i < NFEAT; ++i) f[i] = (int)v[i];
        }
        int rw[16];
        rw[0]  = f[0];
        rw[1]  = R_AB + f[1];
        rw[2]  = R_IT + f[2];
        rw[3]  = R_T1 + f[3] * 4 + f[4] * 2 + f[5];
        rw[4]  = R_T2 + f[6] * 4 + f[11] * 2 + f[12];
        rw[5]  = R_T3 + f[7] * 8 + f[8];
        rw[6]  = R_T4 + f[9] * 2 + f[10];
        rw[7]  = R_T5 + f[13] * 8 + f[14] * 2 + f[15];
        rw[8]  = R_T6 + f[16] * 13 + f[17];
        rw[9]  = R_T7 + f[18] * 13 + f[19];
        rw[10] = R_T8 + f[20] * 13 + f[21];
        rw[11] = R_T9 + f[22];
        rw[12] = R_ACT + f[34];
        rw[13] = R_ACT + f[35];
        rw[14] = R_ACT + f[36];
        rw[15] = R_ACT + f[37];
        unsigned int p[16];
        #pragma unroll
        for (int i = 0; i < 8; ++i)
            p[i] = (unsigned int)rw[2 * i] | ((unsigned int)rw[2 * i + 1] << 16);
        #pragma unroll
        for (int i = 0; i < 5; ++i)
            p[8 + i] = (unsigned int)(f[23 + 2 * i] & 0xffff) | ((unsigned int)f[24 + 2 * i] << 16);
        p[13] = (unsigned int)(f[33] & 0xffff);
        p[14] = 0; p[15] = 0;
        uint4* dst = reinterpret_cast<uint4*>(ridx + (size_t)e * 16);
        dst[0] = make_uint4(p[0], p[1], p[2], p[3]);
        dst[1] = make_uint4(p[4], p[5], p[6], p[7]);
        dst[2] = make_uint4(p[8], p[9], p[10], p[11]);
        dst[3] = make_uint4(p[12], p[13], p[14], p[15]);
    }
#undef W
}

// ---------------------------------------------------------------------------
// K1: fused encode + mlp.  Block = 512 threads (8 waves), 64 entities.
//  A1: wave w gathers 16 rows (8 paired uint4 loads, 1-entity lookahead
//      pipeline) for entities w*8..w*8+7 -> f32 sums in xacc[64][260].
//  A2: bits contribution via MFMA (A = expanded 0/1 bits, B = static wbits
//      fragments), add xacc, relu, bf16 -> xw (overlaid, XOR-swizzled).
//  B : mlp MFMA (A from xw, B from wfrag), bias + species mask, store.
// ---------------------------------------------------------------------------
__global__ __launch_bounds__(512, 4) void k_fused_em(
    const unsigned int* __restrict__ ridx, const unsigned short* __restrict__ tbl,
    const unsigned short* __restrict__ wfrag, const unsigned short* __restrict__ wbits,
    const float* __restrict__ mlp_b, float* __restrict__ out)
{
    __shared__ float xacc[64 * 260];          // 66,560 B (row stride 1040 B)
    __shared__ unsigned int bitw[64 * 6];     // 1,536 B
    __shared__ unsigned char smask[64];
    int t    = threadIdx.x;
    int w    = t >> 6;
    int lane = t & 63;
    int half = lane >> 5;
    int cp   = lane & 31;
    int wu   = __builtin_amdgcn_readfirstlane(w);
    int eb   = blockIdx.x << 6;
    const char* tb = reinterpret_cast<const char*>(tbl);

    // stage bitwords + species mask
    if (t < 384) {
        int e = t / 6, k = t - e * 6;
        bitw[t] = ridx[(size_t)(eb + e) * 16 + 8 + k];
    }
    if (t < 64) smask[t] = ((ridx[(size_t)(eb + t) * 16] & 0xffffu) < 2u) ? 1 : 0;

    // ---------------- A1: gather-encode 8 entities -> xacc (f32) ------------
    {
        int cb = cp << 4;
        const unsigned int* rq0 = ridx + (size_t)(eb + (wu << 3)) * 16;
        uint4 v[8], vn[8];
        #pragma unroll
        for (int j = 0; j < 8; ++j) {
            unsigned int pj = rq0[j];
            unsigned int row = half ? (pj >> 16) : (pj & 0xffffu);
            v[j] = *reinterpret_cast<const uint4*>(tb + ((size_t)row << 9) + cb);
        }
        for (int i = 0; i < 8; ++i) {
            if (i < 7) {
                const unsigned int* rq = rq0 + ((i + 1) << 4);
                #pragma unroll
                for (int j = 0; j < 8; ++j) {
                    unsigned int pj = rq[j];
                    unsigned int row = half ? (pj >> 16) : (pj & 0xffffu);
                    vn[j] = *reinterpret_cast<const uint4*>(tb + ((size_t)row << 9) + cb);
                }
            }
            f32x2 aE0 = (f32x2){0.f, 0.f}, aO0 = (f32x2){0.f, 0.f};
            f32x2 aE1 = (f32x2){0.f, 0.f}, aO1 = (f32x2){0.f, 0.f};
            #pragma unroll
            for (int j = 0; j < 8; ++j) {
                aE0 += (f32x2){__uint_as_float(v[j].x << 16),         __uint_as_float(v[j].y << 16)};
                aO0 += (f32x2){__uint_as_float(v[j].x & 0xffff0000u), __uint_as_float(v[j].y & 0xffff0000u)};
                aE1 += (f32x2){__uint_as_float(v[j].z << 16),         __uint_as_float(v[j].w << 16)};
                aO1 += (f32x2){__uint_as_float(v[j].z & 0xffff0000u), __uint_as_float(v[j].w & 0xffff0000u)};
            }
            float s0 = aE0[0] + __shfl_xor(aE0[0], 32);
            float s1 = aO0[0] + __shfl_xor(aO0[0], 32);
            float s2 = aE0[1] + __shfl_xor(aE0[1], 32);
            float s3 = aO0[1] + __shfl_xor(aO0[1], 32);
            float s4 = aE1[0] + __shfl_xor(aE1[0], 32);
            float s5 = aO1[0] + __shfl_xor(aO1[0], 32);
            float s6 = aE1[1] + __shfl_xor(aE1[1], 32);
            float s7 = aO1[1] + __shfl_xor(aO1[1], 32);
            if (half == 0) {
                int el = (wu << 3) + i;
                float* dst = xacc + el * 260 + (cp << 3);
                *reinterpret_cast<float4*>(dst)     = make_float4(s0, s1, s2, s3);
                *reinterpret_cast<float4*>(dst + 4) = make_float4(s4, s5, s6, s7);
            }
            #pragma unroll
            for (int j = 0; j < 8; ++j) v[j] = vn[j];
        }
    }
    __syncthreads();

    // ---------------- A2: bits via MFMA + add + relu -> bf16 ----------------
    int rc  = lane & 15;
    int kg  = lane >> 4;
    int nt0 = wu << 1;

    f32x4 D0[4], D1[4];
    #pragma unroll
    for (int mt = 0; mt < 4; ++mt) { D0[mt] = (f32x4){0.f,0.f,0.f,0.f}; D1[mt] = (f32x4){0.f,0.f,0.f,0.f}; }

    #pragma unroll
    for (int kt = 0; kt < 6; ++kt) {
        bf16x8 b0 = *reinterpret_cast<const bf16x8*>(wbits + (((size_t)(nt0 * 6 + kt)) << 9) + (lane << 3));
        bf16x8 b1 = *reinterpret_cast<const bf16x8*>(wbits + (((size_t)((nt0 + 1) * 6 + kt)) << 9) + (lane << 3));
        #pragma unroll
        for (int mt = 0; mt < 4; ++mt) {
            unsigned int wb = bitw[((mt << 4) + rc) * 6 + kt];
            unsigned int bs = wb >> (kg << 3);
            unsigned int e0 = ((bs & 1u)   ? 0x3F80u : 0u) | ((bs & 2u)   ? 0x3F800000u : 0u);
            unsigned int e1 = ((bs & 4u)   ? 0x3F80u : 0u) | ((bs & 8u)   ? 0x3F800000u : 0u);
            unsigned int e2 = ((bs & 16u)  ? 0x3F80u : 0u) | ((bs & 32u)  ? 0x3F800000u : 0u);
            unsigned int e3 = ((bs & 64u)  ? 0x3F80u : 0u) | ((bs & 128u) ? 0x3F800000u : 0u);
            bf16x8 afr = __builtin_bit_cast(bf16x8, (u32x4){e0, e1, e2, e3});
            D0[mt] = __builtin_amdgcn_mfma_f32_16x16x32_bf16(afr, b0, D0[mt], 0, 0, 0);
            D1[mt] = __builtin_amdgcn_mfma_f32_16x16x32_bf16(afr, b1, D1[mt], 0, 0, 0);
        }
    }

    unsigned short ov[32];
    #pragma unroll
    for (int mt = 0; mt < 4; ++mt) {
        #pragma unroll
        for (int j = 0; j < 4; ++j) {
            int row = (mt << 4) + (kg << 2) + j;
            int c0  = (wu << 5) + rc;
            float sA = xacc[row * 260 + c0]      + D0[mt][j];
            float sB = xacc[row * 260 + c0 + 16] + D1[mt][j];
            ov[(mt << 3) + j]     = f2bf(fmaxf(sA, 0.f));
            ov[(mt << 3) + 4 + j] = f2bf(fmaxf(sB, 0.f));
        }
    }
    __syncthreads();

    char* xb = reinterpret_cast<char*>(xacc);
    #pragma unroll
    for (int mt = 0; mt < 4; ++mt) {
        #pragma unroll
        for (int j = 0; j < 4; ++j) {
            int row = (mt << 4) + (kg << 2) + j;
            int colA = (wu << 5) + rc;
            int colB = colA + 16;
            int uA = (colA >> 3) ^ (row & 7);
            int uB = (colB >> 3) ^ (row & 7);
            *reinterpret_cast<unsigned short*>(xb + (row << 9) + (uA << 4) + ((colA & 7) << 1)) = ov[(mt << 3) + j];
            *reinterpret_cast<unsigned short*>(xb + (row << 9) + (uB << 4) + ((colB & 7) << 1)) = ov[(mt << 3) + 4 + j];
        }
    }
    __syncthreads();

    // ---------------- B: mlp MFMA, 64 rows x 32 cols per wave ---------------
    f32x4 acc0[4], acc1[4];
    #pragma unroll
    for (int mt = 0; mt < 4; ++mt) {
        acc0[mt] = (f32x4){0.f,0.f,0.f,0.f};
        acc1[mt] = (f32x4){0.f,0.f,0.f,0.f};
    }

    #pragma unroll
    for (int k0g = 0; k0g < 8; ++k0g) {
        bf16x8 b0 = *reinterpret_cast<const bf16x8*>(
            wfrag + (((size_t)(nt0 * 8 + k0g)) << 9) + (lane << 3));
        bf16x8 b1 = *reinterpret_cast<const bf16x8*>(
            wfrag + (((size_t)((nt0 + 1) * 8 + k0g)) << 9) + (lane << 3));
        int up = ((k0g << 2) + kg) ^ (rc & 7);
        #pragma unroll
        for (int mt = 0; mt < 4; ++mt) {
            int r = (mt << 4) + rc;
            bf16x8 a = *reinterpret_cast<const bf16x8*>(xb + (r << 9) + (up << 4));
            acc0[mt] = __builtin_amdgcn_mfma_f32_16x16x32_bf16(a, b0, acc0[mt], 0, 0, 0);
            acc1[mt] = __builtin_amdgcn_mfma_f32_16x16x32_bf16(a, b1, acc1[mt], 0, 0, 0);
        }
    }

    int c0 = wu << 5;
    float bias0 = mlp_b[c0 + rc];
    float bias1 = mlp_b[c0 + 16 + rc];
    #pragma unroll
    for (int mt = 0; mt < 4; ++mt) {
        unsigned int mw = *reinterpret_cast<const unsigned int*>(&smask[(mt << 4) + (kg << 2)]);
        #pragma unroll
        for (int j = 0; j < 4; ++j) {
            int row = eb + (mt << 4) + (kg << 2) + j;
            bool m = (mw >> (8 * j)) & 1u;
            out[(size_t)row * 256 + c0 + rc]      = m ? 0.f : (acc0[mt][j] + bias0);
            out[(size_t)row * 256 + c0 + 16 + rc] = m ? 0.f : (acc1[mt][j] + bias1);
        }
    }
}

// ---------------------------------------------------------------------------
extern "C" void kernel_launch(void* const* d_in, const int* in_sizes, int n_in,
                              void* d_out, int out_size, void* d_ws, size_t ws_size,
                              hipStream_t stream)
{
    const int*   ent     = (const int*)d_in[0];
    const float* sp_tbl  = (const float*)d_in[1];
    const float* ab_tbl  = (const float*)d_in[2];
    const float* it_tbl  = (const float*)d_in[3];
    const float* sp_emb  = (const float*)d_in[4];
    const float* ab_emb  = (const float*)d_in[5];
    const float* it_emb  = (const float*)d_in[6];
    const float* act_emb = (const float*)d_in[7];
    const float* agg_w   = (const float*)d_in[8];
    const float* agg_b   = (const float*)d_in[9];
    const float* mlp_w   = (const float*)d_in[10];
    const float* mlp_b   = (const float*)d_in[11];
    float* out = (float*)d_out;

    char* ws = (char*)d_ws;
    unsigned short* tbl   = (unsigned short*)(ws);               // 2580*512   = 1,320,960 B
    unsigned short* wfrag = (unsigned short*)(ws + 1320960);     //   131,072 B
    unsigned short* wbits = (unsigned short*)(ws + 1452032);     //    98,304 B
    unsigned int*   ridx  = (unsigned int*)  (ws + 1550336);     // 65536*64   = 4,194,304 B

    k_prep    <<<dim3(NB_PREP), dim3(1024), 0, stream>>>(sp_tbl, ab_tbl, it_tbl,
                                                         sp_emb, ab_emb, it_emb,
                                                         act_emb, agg_w, agg_b, mlp_w,
                                                         ent, tbl, wfrag, wbits, ridx);
    k_fused_em<<<dim3(1024),    dim3(512),  0, stream>>>(ridx, tbl, wfrag, wbits, mlp_b, out);
}